// Round 1
// baseline (5823.908 us; speedup 1.0000x reference)
//
#include <hip/hip_runtime.h>

#define NN 100000      // nodes
#define NE 1600000     // edges (without self loops)
#define NF 11          // input features
#define HID 128
#define NG 4096        // graphs

static __device__ __forceinline__ void atomAdd(float* p, float v) {
#if defined(__AMDGCN__)
    unsafeAtomicAdd(p, v);   // hardware global_atomic_add_f32
#else
    atomicAdd(p, v);
#endif
}

// ---- init: deg=1 (self loop), pooled=0, cnt=0 ----
__global__ void k_init(int* degi, float* pooled, int* cnt) {
    int i = blockIdx.x * blockDim.x + threadIdx.x;
    if (i < NN) degi[i] = 1;
    if (i < NG * HID) pooled[i] = 0.f;
    if (i < NG) cnt[i] = 0;
}

// ---- degree over col ----
__global__ void k_deg(const int* __restrict__ col, int* degi) {
    int e = blockIdx.x * blockDim.x + threadIdx.x;
    if (e < NE) atomicAdd(&degi[col[e]], 1);
}

__global__ void k_dis(const int* __restrict__ degi, float* __restrict__ dis) {
    int n = blockIdx.x * blockDim.x + threadIdx.x;
    if (n < NN) dis[n] = rsqrtf((float)degi[n]);
}

// ---- y = (x @ W1) * dis ; 2 nodes per 256-thr block ----
__global__ __launch_bounds__(256) void k_xw1(const float* __restrict__ x, const float* __restrict__ W1,
                                             const float* __restrict__ dis, float* __restrict__ y) {
    __shared__ float w1s[NF * HID];
    __shared__ float xs[2 * NF];
    const int tid = threadIdx.x;
    const int n0 = blockIdx.x * 2;
    for (int i = tid; i < NF * HID; i += 256) w1s[i] = W1[i];
    if (tid < 2 * NF) xs[tid] = x[(size_t)n0 * NF + tid];
    __syncthreads();
    const int nl = tid >> 7, f = tid & 127;
    const int n = n0 + nl;
    float s = 0.f;
#pragma unroll
    for (int k = 0; k < NF; ++k) s += xs[nl * NF + k] * w1s[k * HID + f];
    y[(size_t)n * HID + f] = s * dis[n];
}

// ---- acc = y (self-loop init), float4 ----
__global__ void k_copy(const float4* __restrict__ src, float4* __restrict__ dst) {
    int i = blockIdx.x * blockDim.x + threadIdx.x;
    if (i < NN * (HID / 4)) dst[i] = src[i];
}

// ---- scatter: acc[col] += y[row], one float4 per thread ----
__global__ __launch_bounds__(256) void k_scatter(const int* __restrict__ row, const int* __restrict__ col,
                                                 const float* __restrict__ y, float* __restrict__ acc) {
    int idx = blockIdx.x * 256 + threadIdx.x;           // NE*32 = 51.2M < 2^31
    int e = idx >> 5, q = idx & 31;
    if (e >= NE) return;
    int r = row[e], c = col[e];
    float4 v = ((const float4*)y)[r * 32 + q];
    float* a = acc + (size_t)c * HID + q * 4;
    atomAdd(a + 0, v.x); atomAdd(a + 1, v.y); atomAdd(a + 2, v.z); atomAdd(a + 3, v.w);
}

// ---- h = relu(acc * dis[n] + b) in place ----
__global__ void k_bias_relu(float* __restrict__ acc, const float* __restrict__ b,
                            const float* __restrict__ dis) {
    int idx = blockIdx.x * blockDim.x + threadIdx.x;    // NN*32
    if (idx >= NN * 32) return;
    int n = idx >> 5, q = idx & 31;
    float d = dis[n];
    float4 v = ((float4*)acc)[idx];
    float4 bb = ((const float4*)b)[q];
    v.x = fmaxf(fmaf(v.x, d, bb.x), 0.f);
    v.y = fmaxf(fmaf(v.y, d, bb.y), 0.f);
    v.z = fmaxf(fmaf(v.z, d, bb.z), 0.f);
    v.w = fmaxf(fmaf(v.w, d, bb.w), 0.f);
    ((float4*)acc)[idx] = v;
}

// ---- y2 = (h @ W2) * dis ; 32 nodes/block, W2+h tile in LDS ----
__global__ __launch_bounds__(256) void k_xw2(const float* __restrict__ h, const float* __restrict__ W2,
                                             const float* __restrict__ dis, float* __restrict__ y) {
    __shared__ float w2s[HID * HID];   // 64 KB
    __shared__ float hs[32 * HID];     // 16 KB
    const int tid = threadIdx.x;
    const int n0 = blockIdx.x * 32;
    for (int i = tid; i < HID * HID; i += 256) w2s[i] = W2[i];
    for (int i = tid; i < 32 * HID; i += 256) hs[i] = h[(size_t)n0 * HID + i];
    __syncthreads();
    const int f4 = tid & 31;   // feature quad: f = f4*4
    const int g = tid >> 5;    // node group: nodes n0+g*4 .. +3
    float4 acc[4];
#pragma unroll
    for (int j = 0; j < 4; ++j) acc[j] = make_float4(0.f, 0.f, 0.f, 0.f);
    const float4* w4 = (const float4*)w2s;  // [128][32]
    const float4* h4 = (const float4*)hs;   // [32][32]
    for (int k4 = 0; k4 < 32; ++k4) {
        float4 hv[4];
#pragma unroll
        for (int j = 0; j < 4; ++j) hv[j] = h4[(g * 4 + j) * 32 + k4];
#pragma unroll
        for (int kk = 0; kk < 4; ++kk) {
            float4 wv = w4[(k4 * 4 + kk) * 32 + f4];
#pragma unroll
            for (int j = 0; j < 4; ++j) {
                float hj = (&hv[j].x)[kk];
                acc[j].x = fmaf(hj, wv.x, acc[j].x);
                acc[j].y = fmaf(hj, wv.y, acc[j].y);
                acc[j].z = fmaf(hj, wv.z, acc[j].z);
                acc[j].w = fmaf(hj, wv.w, acc[j].w);
            }
        }
    }
#pragma unroll
    for (int j = 0; j < 4; ++j) {
        int n = n0 + g * 4 + j;
        float d = dis[n];
        float4 o = make_float4(acc[j].x * d, acc[j].y * d, acc[j].z * d, acc[j].w * d);
        ((float4*)y)[(size_t)n * 32 + f4] = o;
    }
}

// ---- pooling ----
__global__ void k_pool_cnt(const int* __restrict__ batch, int* cnt) {
    int n = blockIdx.x * blockDim.x + threadIdx.x;
    if (n < NN) atomicAdd(&cnt[batch[n]], 1);
}

__global__ void k_pool_sum(const float* __restrict__ h, const int* __restrict__ batch,
                           float* __restrict__ pooled) {
    int idx = blockIdx.x * blockDim.x + threadIdx.x;    // NN*32
    if (idx >= NN * 32) return;
    int n = idx >> 5, q = idx & 31;
    int g = batch[n];
    float4 v = ((const float4*)h)[idx];
    float* p = pooled + (size_t)g * HID + q * 4;
    atomAdd(p + 0, v.x); atomAdd(p + 1, v.y); atomAdd(p + 2, v.z); atomAdd(p + 3, v.w);
}

// ---- head: out = relu(pooled/cnt @ Wl1 + bl1) @ Wl2 + bl2 ----
__global__ __launch_bounds__(128) void k_head(const float* __restrict__ pooled, const int* __restrict__ cnt,
                                              const float* __restrict__ Wl1, const float* __restrict__ bl1,
                                              const float* __restrict__ Wl2, const float* __restrict__ bl2,
                                              float* __restrict__ out) {
    __shared__ float p[HID];
    __shared__ float red[128];
    const int g = blockIdx.x, f = threadIdx.x;
    float invc = 1.0f / (float)max(cnt[g], 1);
    p[f] = pooled[(size_t)g * HID + f] * invc;
    __syncthreads();
    float s = bl1[f];
    for (int k = 0; k < HID; ++k) s = fmaf(p[k], Wl1[k * HID + f], s);
    s = fmaxf(s, 0.f);
    red[f] = s * Wl2[f];
    __syncthreads();
    for (int off = 64; off > 0; off >>= 1) {
        if (f < off) red[f] += red[f + off];
        __syncthreads();
    }
    if (f == 0) out[g] = red[0] + bl2[0];
}

extern "C" void kernel_launch(void* const* d_in, const int* in_sizes, int n_in,
                              void* d_out, int out_size, void* d_ws, size_t ws_size,
                              hipStream_t stream) {
    const float* x   = (const float*)d_in[0];
    const float* W1  = (const float*)d_in[1];
    const float* b1  = (const float*)d_in[2];
    const float* W2  = (const float*)d_in[3];
    const float* b2  = (const float*)d_in[4];
    const float* Wl1 = (const float*)d_in[5];
    const float* bl1 = (const float*)d_in[6];
    const float* Wl2 = (const float*)d_in[7];
    const float* bl2 = (const float*)d_in[8];
    const int* ei    = (const int*)d_in[9];     // [2][NE]
    const int* batch = (const int*)d_in[10];
    float* out = (float*)d_out;

    const int* row = ei;
    const int* col = ei + NE;

    // workspace layout (bytes)
    char* ws = (char*)d_ws;
    float* y      = (float*)(ws);                                   // 51.2 MB
    float* acc    = (float*)(ws + (size_t)NN * HID * 4);            // 51.2 MB
    float* dis    = (float*)(ws + (size_t)2 * NN * HID * 4);        // 400 KB
    int*   degi   = (int*)  (ws + (size_t)2 * NN * HID * 4 + (size_t)NN * 4);
    float* pooled = (float*)(ws + (size_t)2 * NN * HID * 4 + (size_t)2 * NN * 4);
    int*   cnt    = (int*)  (ws + (size_t)2 * NN * HID * 4 + (size_t)2 * NN * 4 + (size_t)NG * HID * 4);

    k_init<<<(NG * HID + 255) / 256, 256, 0, stream>>>(degi, pooled, cnt);
    k_deg<<<(NE + 255) / 256, 256, 0, stream>>>(col, degi);
    k_dis<<<(NN + 255) / 256, 256, 0, stream>>>(degi, dis);

    // layer 1
    k_xw1<<<NN / 2, 256, 0, stream>>>(x, W1, dis, y);
    k_copy<<<(NN * 32 + 255) / 256, 256, 0, stream>>>((const float4*)y, (float4*)acc);
    k_scatter<<<(NE * 32) / 256, 256, 0, stream>>>(row, col, y, acc);
    k_bias_relu<<<(NN * 32 + 255) / 256, 256, 0, stream>>>(acc, b1, dis);

    // layer 2
    k_xw2<<<NN / 32, 256, 0, stream>>>(acc, W2, dis, y);
    k_copy<<<(NN * 32 + 255) / 256, 256, 0, stream>>>((const float4*)y, (float4*)acc);
    k_scatter<<<(NE * 32) / 256, 256, 0, stream>>>(row, col, y, acc);
    k_bias_relu<<<(NN * 32 + 255) / 256, 256, 0, stream>>>(acc, b2, dis);

    // pool + head
    k_pool_cnt<<<(NN + 255) / 256, 256, 0, stream>>>(batch, cnt);
    k_pool_sum<<<(NN * 32 + 255) / 256, 256, 0, stream>>>(acc, batch, pooled);
    k_head<<<NG, 128, 0, stream>>>(pooled, cnt, Wl1, bl1, Wl2, bl2, out);
}

// Round 2
// 558.369 us; speedup vs baseline: 10.4302x; 10.4302x over previous
//
#include <hip/hip_runtime.h>

#define NN 100000      // nodes
#define NE 1600000     // edges (without self loops)
#define NF 11          // input features
#define HID 128
#define NG 4096        // graphs
#define NB 391         // scan blocks = ceil(NN/256)

// ---- zero edge-degree ----
__global__ void k_zero(int* __restrict__ degE) {
    int i = blockIdx.x * blockDim.x + threadIdx.x;
    if (i < NN) degE[i] = 0;
}

// ---- histogram of incoming edges per node ----
__global__ void k_deg(const int* __restrict__ col, int* __restrict__ degE) {
    int e = blockIdx.x * blockDim.x + threadIdx.x;
    if (e < NE) atomicAdd(&degE[col[e]], 1);
}

// ---- dis = rsqrt(degE + 1)  (self loop included in norm degree) ----
__global__ void k_dis(const int* __restrict__ degE, float* __restrict__ dis) {
    int n = blockIdx.x * blockDim.x + threadIdx.x;
    if (n < NN) dis[n] = rsqrtf((float)(degE[n] + 1));
}

// ---- 3-phase exclusive scan of degE -> startp ----
__global__ void k_scan1(const int* __restrict__ degE, int* __restrict__ startp, int* __restrict__ partial) {
    __shared__ int sh[256];
    int t = threadIdx.x, i = blockIdx.x * 256 + t;
    int v = (i < NN) ? degE[i] : 0;
    sh[t] = v; __syncthreads();
    for (int off = 1; off < 256; off <<= 1) {
        int u = (t >= off) ? sh[t - off] : 0; __syncthreads();
        sh[t] += u; __syncthreads();
    }
    if (i < NN) startp[i] = sh[t] - v;          // exclusive (no global offset yet)
    if (t == 255) partial[blockIdx.x] = sh[255];
}

__global__ void k_scan2(int* __restrict__ partial) {   // 1 block, 512 thr
    __shared__ int sh[512];
    int t = threadIdx.x;
    int v = (t < NB) ? partial[t] : 0;
    sh[t] = v; __syncthreads();
    for (int off = 1; off < 512; off <<= 1) {
        int u = (t >= off) ? sh[t - off] : 0; __syncthreads();
        sh[t] += u; __syncthreads();
    }
    if (t < NB) partial[t] = sh[t] - v;          // exclusive
}

__global__ void k_scan3(int* __restrict__ startp, const int* __restrict__ partial, int* __restrict__ cursor) {
    int i = blockIdx.x * 256 + threadIdx.x;
    if (i < NN) {
        int s = startp[i] + partial[blockIdx.x];
        startp[i] = s;
        cursor[i] = s;
    }
    if (i == 0) startp[NN] = NE;
}

// ---- fill CSR rows ----
__global__ void k_fill(const int* __restrict__ row, const int* __restrict__ col,
                       int* __restrict__ cursor, int* __restrict__ csr_rows) {
    int e = blockIdx.x * blockDim.x + threadIdx.x;
    if (e < NE) {
        int pos = atomicAdd(&cursor[col[e]], 1);
        csr_rows[pos] = row[e];
    }
}

// ---- y = (x @ W1) * dis ; 16 nodes per 256-thr block ----
__global__ __launch_bounds__(256) void k_xw1(const float* __restrict__ x, const float* __restrict__ W1,
                                             const float* __restrict__ dis, float* __restrict__ y) {
    __shared__ float w1s[NF * HID];
    __shared__ float xs[16 * NF];
    const int tid = threadIdx.x;
    const int n0 = blockIdx.x * 16;
    for (int i = tid; i < NF * HID; i += 256) w1s[i] = W1[i];
    for (int i = tid; i < 16 * NF; i += 256) xs[i] = x[(size_t)n0 * NF + i];
    __syncthreads();
    const int f = tid & 127, half = tid >> 7;
#pragma unroll
    for (int p = 0; p < 8; ++p) {
        int nl = p * 2 + half;
        float s = 0.f;
#pragma unroll
        for (int k = 0; k < NF; ++k) s = fmaf(xs[nl * NF + k], w1s[k * HID + f], s);
        int n = n0 + nl;
        y[(size_t)n * HID + f] = s * dis[n];
    }
}

// ---- gather conv: out[c] = relu(dis[c]*(y[c] + sum_e y[rows[e]]) + b)
//      one wave per node, float2 per lane ----
__global__ __launch_bounds__(256) void k_gather(const float* __restrict__ y,
                                                const int* __restrict__ startp,
                                                const int* __restrict__ csr_rows,
                                                const float* __restrict__ dis,
                                                const float* __restrict__ b,
                                                float* __restrict__ out) {
    const int node = blockIdx.x * 4 + (threadIdx.x >> 6);
    const int lane = threadIdx.x & 63;
    const float2* y2 = (const float2*)y;
    int s = startp[node], e = startp[node + 1];
    float2 acc = y2[node * 64 + lane];            // self loop
    for (int i = s; i < e; i += 64) {
        int idx = (i + lane < e) ? csr_rows[i + lane] : 0;
        int m = min(64, e - i);
        int j = 0;
        for (; j + 3 < m; j += 4) {
            int r0 = __shfl(idx, j), r1 = __shfl(idx, j + 1);
            int r2 = __shfl(idx, j + 2), r3 = __shfl(idx, j + 3);
            float2 v0 = y2[r0 * 64 + lane], v1 = y2[r1 * 64 + lane];
            float2 v2 = y2[r2 * 64 + lane], v3 = y2[r3 * 64 + lane];
            acc.x += (v0.x + v1.x) + (v2.x + v3.x);
            acc.y += (v0.y + v1.y) + (v2.y + v3.y);
        }
        for (; j < m; ++j) {
            int r = __shfl(idx, j);
            float2 v = y2[r * 64 + lane];
            acc.x += v.x; acc.y += v.y;
        }
    }
    float d = dis[node];
    float2 bb = ((const float2*)b)[lane];
    acc.x = fmaxf(fmaf(acc.x, d, bb.x), 0.f);
    acc.y = fmaxf(fmaf(acc.y, d, bb.y), 0.f);
    ((float2*)out)[node * 64 + lane] = acc;
}

// ---- y2 = (h @ W2) * dis ; 32 nodes/block, W2+h tile in LDS ----
__global__ __launch_bounds__(256) void k_xw2(const float* __restrict__ h, const float* __restrict__ W2,
                                             const float* __restrict__ dis, float* __restrict__ y) {
    __shared__ float w2s[HID * HID];   // 64 KB
    __shared__ float hs[32 * HID];     // 16 KB
    const int tid = threadIdx.x;
    const int n0 = blockIdx.x * 32;
    for (int i = tid; i < HID * HID; i += 256) w2s[i] = W2[i];
    for (int i = tid; i < 32 * HID; i += 256) hs[i] = h[(size_t)n0 * HID + i];
    __syncthreads();
    const int f4 = tid & 31;
    const int g = tid >> 5;
    float4 acc[4];
#pragma unroll
    for (int j = 0; j < 4; ++j) acc[j] = make_float4(0.f, 0.f, 0.f, 0.f);
    const float4* w4 = (const float4*)w2s;
    const float4* h4 = (const float4*)hs;
    for (int k4 = 0; k4 < 32; ++k4) {
        float4 hv[4];
#pragma unroll
        for (int j = 0; j < 4; ++j) hv[j] = h4[(g * 4 + j) * 32 + k4];
#pragma unroll
        for (int kk = 0; kk < 4; ++kk) {
            float4 wv = w4[(k4 * 4 + kk) * 32 + f4];
#pragma unroll
            for (int j = 0; j < 4; ++j) {
                float hj = (&hv[j].x)[kk];
                acc[j].x = fmaf(hj, wv.x, acc[j].x);
                acc[j].y = fmaf(hj, wv.y, acc[j].y);
                acc[j].z = fmaf(hj, wv.z, acc[j].z);
                acc[j].w = fmaf(hj, wv.w, acc[j].w);
            }
        }
    }
#pragma unroll
    for (int j = 0; j < 4; ++j) {
        int n = n0 + g * 4 + j;
        float d = dis[n];
        ((float4*)y)[(size_t)n * 32 + f4] =
            make_float4(acc[j].x * d, acc[j].y * d, acc[j].z * d, acc[j].w * d);
    }
}

// ---- graph segment bounds on sorted batch ----
__global__ void k_bounds(const int* __restrict__ batch, int* __restrict__ gs) {
    int g = blockIdx.x * blockDim.x + threadIdx.x;
    if (g > NG) return;
    int lo = 0, hi = NN;
    while (lo < hi) {
        int mid = (lo + hi) >> 1;
        if (batch[mid] < g) lo = mid + 1; else hi = mid;
    }
    gs[g] = lo;
}

// ---- mean pool: block per graph ----
__global__ __launch_bounds__(128) void k_pool(const float* __restrict__ h, const int* __restrict__ gs,
                                              float* __restrict__ pooled) {
    int g = blockIdx.x, f = threadIdx.x;
    int s = gs[g], e = gs[g + 1];
    float acc = 0.f;
    for (int n = s; n < e; ++n) acc += h[(size_t)n * HID + f];
    pooled[(size_t)g * HID + f] = acc / (float)max(e - s, 1);
}

// ---- head: out = relu(pooled @ Wl1 + bl1) @ Wl2 + bl2 ----
__global__ __launch_bounds__(128) void k_head(const float* __restrict__ pooled,
                                              const float* __restrict__ Wl1, const float* __restrict__ bl1,
                                              const float* __restrict__ Wl2, const float* __restrict__ bl2,
                                              float* __restrict__ out) {
    __shared__ float p[HID];
    __shared__ float red[128];
    const int g = blockIdx.x, f = threadIdx.x;
    p[f] = pooled[(size_t)g * HID + f];
    __syncthreads();
    float s = bl1[f];
    for (int k = 0; k < HID; ++k) s = fmaf(p[k], Wl1[k * HID + f], s);
    s = fmaxf(s, 0.f);
    red[f] = s * Wl2[f];
    __syncthreads();
    for (int off = 64; off > 0; off >>= 1) {
        if (f < off) red[f] += red[f + off];
        __syncthreads();
    }
    if (f == 0) out[g] = red[0] + bl2[0];
}

extern "C" void kernel_launch(void* const* d_in, const int* in_sizes, int n_in,
                              void* d_out, int out_size, void* d_ws, size_t ws_size,
                              hipStream_t stream) {
    const float* x   = (const float*)d_in[0];
    const float* W1  = (const float*)d_in[1];
    const float* b1  = (const float*)d_in[2];
    const float* W2  = (const float*)d_in[3];
    const float* b2  = (const float*)d_in[4];
    const float* Wl1 = (const float*)d_in[5];
    const float* bl1 = (const float*)d_in[6];
    const float* Wl2 = (const float*)d_in[7];
    const float* bl2 = (const float*)d_in[8];
    const int* ei    = (const int*)d_in[9];     // [2][NE]
    const int* batch = (const int*)d_in[10];
    float* out = (float*)d_out;

    const int* row = ei;
    const int* col = ei + NE;

    // workspace layout
    char* ws = (char*)d_ws;
    size_t off = 0;
    float* y       = (float*)(ws + off); off += (size_t)NN * HID * 4;   // 51.2 MB
    float* h       = (float*)(ws + off); off += (size_t)NN * HID * 4;   // 51.2 MB
    int*   degE    = (int*)  (ws + off); off += (size_t)NN * 4;
    float* dis     = (float*)(ws + off); off += (size_t)NN * 4;
    int*   startp  = (int*)  (ws + off); off += (size_t)(NN + 1) * 4;
    int*   cursor  = (int*)  (ws + off); off += (size_t)NN * 4;
    int*   partial = (int*)  (ws + off); off += 512 * 4;
    int*   csr     = (int*)  (ws + off); off += (size_t)NE * 4;         // 6.4 MB
    int*   gs      = (int*)  (ws + off); off += (size_t)(NG + 1) * 4;
    float* pooled  = (float*)(ws + off); off += (size_t)NG * HID * 4;   // 2 MB

    // ---- CSR build (shared by both layers) ----
    k_zero<<<NB, 256, 0, stream>>>(degE);
    k_deg<<<(NE + 255) / 256, 256, 0, stream>>>(col, degE);
    k_dis<<<NB, 256, 0, stream>>>(degE, dis);
    k_scan1<<<NB, 256, 0, stream>>>(degE, startp, partial);
    k_scan2<<<1, 512, 0, stream>>>(partial);
    k_scan3<<<NB, 256, 0, stream>>>(startp, partial, cursor);
    k_fill<<<(NE + 255) / 256, 256, 0, stream>>>(row, col, cursor, csr);
    k_bounds<<<(NG + 256) / 256, 256, 0, stream>>>(batch, gs);

    // ---- layer 1 ----
    k_xw1<<<NN / 16, 256, 0, stream>>>(x, W1, dis, y);
    k_gather<<<NN / 4, 256, 0, stream>>>(y, startp, csr, dis, b1, h);

    // ---- layer 2 ----
    k_xw2<<<NN / 32, 256, 0, stream>>>(h, W2, dis, y);
    k_gather<<<NN / 4, 256, 0, stream>>>(y, startp, csr, dis, b2, h);

    // ---- pool + head ----
    k_pool<<<NG, 128, 0, stream>>>(h, gs, pooled);
    k_head<<<NG, 128, 0, stream>>>(pooled, Wl1, bl1, Wl2, bl2, out);
}

// Round 3
// 402.853 us; speedup vs baseline: 14.4567x; 1.3860x over previous
//
#include <hip/hip_runtime.h>

#define NN 100000      // nodes
#define NE 1600000     // edges (without self loops)
#define NF 11          // input features
#define HID 128
#define NG 4096        // graphs
#define NB 391         // scan blocks = ceil(NN/256)

#define BSH 7
#define BNODES 128     // nodes per bucket = 1<<BSH
#define NBK 782        // ceil(NN/BNODES)
#define CAP 3072       // staging capacity per bucket (avg 2048, +22 sigma)
#define EPB 8192       // edges per k_bucket block
#define NBB 196        // ceil(NE/EPB)

// ---- zero ints ----
__global__ void k_zero(int* __restrict__ p, int n) {
    int i = blockIdx.x * blockDim.x + threadIdx.x;
    if (i < n) p[i] = 0;
}

// ---- pass 1: bucket edges by col>>7 into staging (workgroup multisplit) ----
__global__ __launch_bounds__(256) void k_bucket(const int* __restrict__ row, const int* __restrict__ col,
                                                int* __restrict__ bcur, int* __restrict__ staging) {
    __shared__ int cnt[NBK];
    __shared__ int loc[NBK];
    const int tid = threadIdx.x;
    const int e0 = blockIdx.x * EPB;
    for (int i = tid; i < NBK; i += 256) { cnt[i] = 0; loc[i] = 0; }
    __syncthreads();
    int rb[32]; unsigned pay[32];
#pragma unroll
    for (int j = 0; j < 32; ++j) {
        int e = e0 + j * 256 + tid;
        int c = (e < NE) ? col[e] : -1;
        int r = (e < NE) ? row[e] : 0;
        rb[j] = (c >= 0) ? (c >> BSH) : -1;
        pay[j] = (unsigned)r | ((unsigned)(c & (BNODES - 1)) << 17);
        if (rb[j] >= 0) atomicAdd(&cnt[rb[j]], 1);
    }
    __syncthreads();
    for (int b = tid; b < NBK; b += 256) {
        int c = cnt[b];
        cnt[b] = (c > 0) ? atomicAdd(&bcur[b], c) : 0;
    }
    __syncthreads();
#pragma unroll
    for (int j = 0; j < 32; ++j) {
        if (rb[j] >= 0) {
            int p = cnt[rb[j]] + atomicAdd(&loc[rb[j]], 1);
            staging[rb[j] * CAP + p] = (int)pay[j];
        }
    }
}

// ---- pass 2a: per-bucket histogram -> degE, dis (coalesced stores, no global atomics) ----
__global__ __launch_bounds__(256) void k_hist2(const int* __restrict__ staging, const int* __restrict__ bcur,
                                               int* __restrict__ degE, float* __restrict__ dis) {
    __shared__ int cnt[BNODES];
    const int b = blockIdx.x, tid = threadIdx.x;
    if (tid < BNODES) cnt[tid] = 0;
    __syncthreads();
    const int sz = bcur[b];
    const int base = b * CAP;
    for (int i = tid; i < sz; i += 256)
        atomicAdd(&cnt[((unsigned)staging[base + i]) >> 17], 1);
    __syncthreads();
    int n = b * BNODES + tid;
    if (tid < BNODES && n < NN) {
        int d = cnt[tid];
        degE[n] = d;
        dis[n] = rsqrtf((float)(d + 1));
    }
}

// ---- 3-phase exclusive scan of degE -> startp ----
__global__ void k_scan1(const int* __restrict__ degE, int* __restrict__ startp, int* __restrict__ partial) {
    __shared__ int sh[256];
    int t = threadIdx.x, i = blockIdx.x * 256 + t;
    int v = (i < NN) ? degE[i] : 0;
    sh[t] = v; __syncthreads();
    for (int off = 1; off < 256; off <<= 1) {
        int u = (t >= off) ? sh[t - off] : 0; __syncthreads();
        sh[t] += u; __syncthreads();
    }
    if (i < NN) startp[i] = sh[t] - v;
    if (t == 255) partial[blockIdx.x] = sh[255];
}

__global__ void k_scan2(int* __restrict__ partial) {   // 1 block, 512 thr
    __shared__ int sh[512];
    int t = threadIdx.x;
    int v = (t < NB) ? partial[t] : 0;
    sh[t] = v; __syncthreads();
    for (int off = 1; off < 512; off <<= 1) {
        int u = (t >= off) ? sh[t - off] : 0; __syncthreads();
        sh[t] += u; __syncthreads();
    }
    if (t < NB) partial[t] = sh[t] - v;
}

__global__ void k_scan3(int* __restrict__ startp, const int* __restrict__ partial) {
    int i = blockIdx.x * 256 + threadIdx.x;
    if (i < NN) startp[i] += partial[blockIdx.x];
    if (i == 0) startp[NN] = NE;
}

// ---- pass 2b: per-bucket counting sort into final CSR (writes stay in an 8KB window) ----
__global__ __launch_bounds__(256) void k_fillb(const int* __restrict__ staging, const int* __restrict__ bcur,
                                               const int* __restrict__ startp, int* __restrict__ csr) {
    __shared__ int cur[BNODES];
    const int b = blockIdx.x, tid = threadIdx.x;
    int n = b * BNODES + tid;
    if (tid < BNODES) cur[tid] = (n < NN) ? startp[n] : 0;
    __syncthreads();
    const int sz = bcur[b];
    const int base = b * CAP;
    for (int i = tid; i < sz; i += 256) {
        unsigned p = (unsigned)staging[base + i];
        int pos = atomicAdd(&cur[p >> 17], 1);
        csr[pos] = (int)(p & 0x1FFFF);
    }
}

// ---- y = (x @ W1) * dis ; 16 nodes per 256-thr block ----
__global__ __launch_bounds__(256) void k_xw1(const float* __restrict__ x, const float* __restrict__ W1,
                                             const float* __restrict__ dis, float* __restrict__ y) {
    __shared__ float w1s[NF * HID];
    __shared__ float xs[16 * NF];
    const int tid = threadIdx.x;
    const int n0 = blockIdx.x * 16;
    for (int i = tid; i < NF * HID; i += 256) w1s[i] = W1[i];
    for (int i = tid; i < 16 * NF; i += 256) xs[i] = x[(size_t)n0 * NF + i];
    __syncthreads();
    const int f = tid & 127, half = tid >> 7;
#pragma unroll
    for (int p = 0; p < 8; ++p) {
        int nl = p * 2 + half;
        float s = 0.f;
#pragma unroll
        for (int k = 0; k < NF; ++k) s = fmaf(xs[nl * NF + k], w1s[k * HID + f], s);
        int n = n0 + nl;
        y[(size_t)n * HID + f] = s * dis[n];
    }
}

// ---- gather conv: out[c] = relu(dis[c]*(y[c] + sum_e y[rows[e]]) + b) ----
__global__ __launch_bounds__(256) void k_gather(const float* __restrict__ y,
                                                const int* __restrict__ startp,
                                                const int* __restrict__ csr_rows,
                                                const float* __restrict__ dis,
                                                const float* __restrict__ b,
                                                float* __restrict__ out) {
    const int node = blockIdx.x * 4 + (threadIdx.x >> 6);
    const int lane = threadIdx.x & 63;
    const float2* y2 = (const float2*)y;
    int s = startp[node], e = startp[node + 1];
    float2 acc = y2[node * 64 + lane];            // self loop
    for (int i = s; i < e; i += 64) {
        int idx = (i + lane < e) ? csr_rows[i + lane] : 0;
        int m = min(64, e - i);
        int j = 0;
        for (; j + 7 < m; j += 8) {
            float2 v[8];
#pragma unroll
            for (int u = 0; u < 8; ++u) {
                int r = __shfl(idx, j + u);
                v[u] = y2[r * 64 + lane];
            }
#pragma unroll
            for (int u = 0; u < 8; ++u) { acc.x += v[u].x; acc.y += v[u].y; }
        }
        for (; j + 3 < m; j += 4) {
            float2 v[4];
#pragma unroll
            for (int u = 0; u < 4; ++u) {
                int r = __shfl(idx, j + u);
                v[u] = y2[r * 64 + lane];
            }
#pragma unroll
            for (int u = 0; u < 4; ++u) { acc.x += v[u].x; acc.y += v[u].y; }
        }
        for (; j < m; ++j) {
            int r = __shfl(idx, j);
            float2 v = y2[r * 64 + lane];
            acc.x += v.x; acc.y += v.y;
        }
    }
    float d = dis[node];
    float2 bb = ((const float2*)b)[lane];
    acc.x = fmaxf(fmaf(acc.x, d, bb.x), 0.f);
    acc.y = fmaxf(fmaf(acc.y, d, bb.y), 0.f);
    ((float2*)out)[node * 64 + lane] = acc;
}

// ---- y2 = (h @ W2) * dis ; 32 nodes/block, W2+h tile in LDS ----
__global__ __launch_bounds__(256) void k_xw2(const float* __restrict__ h, const float* __restrict__ W2,
                                             const float* __restrict__ dis, float* __restrict__ y) {
    __shared__ float w2s[HID * HID];   // 64 KB
    __shared__ float hs[32 * HID];     // 16 KB
    const int tid = threadIdx.x;
    const int n0 = blockIdx.x * 32;
    for (int i = tid; i < HID * HID; i += 256) w2s[i] = W2[i];
    for (int i = tid; i < 32 * HID; i += 256) hs[i] = h[(size_t)n0 * HID + i];
    __syncthreads();
    const int f4 = tid & 31;
    const int g = tid >> 5;
    float4 acc[4];
#pragma unroll
    for (int j = 0; j < 4; ++j) acc[j] = make_float4(0.f, 0.f, 0.f, 0.f);
    const float4* w4 = (const float4*)w2s;
    const float4* h4 = (const float4*)hs;
    for (int k4 = 0; k4 < 32; ++k4) {
        float4 hv[4];
#pragma unroll
        for (int j = 0; j < 4; ++j) hv[j] = h4[(g * 4 + j) * 32 + k4];
#pragma unroll
        for (int kk = 0; kk < 4; ++kk) {
            float4 wv = w4[(k4 * 4 + kk) * 32 + f4];
#pragma unroll
            for (int j = 0; j < 4; ++j) {
                float hj = (&hv[j].x)[kk];
                acc[j].x = fmaf(hj, wv.x, acc[j].x);
                acc[j].y = fmaf(hj, wv.y, acc[j].y);
                acc[j].z = fmaf(hj, wv.z, acc[j].z);
                acc[j].w = fmaf(hj, wv.w, acc[j].w);
            }
        }
    }
#pragma unroll
    for (int j = 0; j < 4; ++j) {
        int n = n0 + g * 4 + j;
        float d = dis[n];
        ((float4*)y)[(size_t)n * 32 + f4] =
            make_float4(acc[j].x * d, acc[j].y * d, acc[j].z * d, acc[j].w * d);
    }
}

// ---- graph segment bounds on sorted batch ----
__global__ void k_bounds(const int* __restrict__ batch, int* __restrict__ gs) {
    int g = blockIdx.x * blockDim.x + threadIdx.x;
    if (g > NG) return;
    int lo = 0, hi = NN;
    while (lo < hi) {
        int mid = (lo + hi) >> 1;
        if (batch[mid] < g) lo = mid + 1; else hi = mid;
    }
    gs[g] = lo;
}

// ---- mean pool: block per graph ----
__global__ __launch_bounds__(128) void k_pool(const float* __restrict__ h, const int* __restrict__ gs,
                                              float* __restrict__ pooled) {
    int g = blockIdx.x, f = threadIdx.x;
    int s = gs[g], e = gs[g + 1];
    float acc = 0.f;
    for (int n = s; n < e; ++n) acc += h[(size_t)n * HID + f];
    pooled[(size_t)g * HID + f] = acc / (float)max(e - s, 1);
}

// ---- head: out = relu(pooled @ Wl1 + bl1) @ Wl2 + bl2 ----
__global__ __launch_bounds__(128) void k_head(const float* __restrict__ pooled,
                                              const float* __restrict__ Wl1, const float* __restrict__ bl1,
                                              const float* __restrict__ Wl2, const float* __restrict__ bl2,
                                              float* __restrict__ out) {
    __shared__ float p[HID];
    __shared__ float red[128];
    const int g = blockIdx.x, f = threadIdx.x;
    p[f] = pooled[(size_t)g * HID + f];
    __syncthreads();
    float s = bl1[f];
    for (int k = 0; k < HID; ++k) s = fmaf(p[k], Wl1[k * HID + f], s);
    s = fmaxf(s, 0.f);
    red[f] = s * Wl2[f];
    __syncthreads();
    for (int off = 64; off > 0; off >>= 1) {
        if (f < off) red[f] += red[f + off];
        __syncthreads();
    }
    if (f == 0) out[g] = red[0] + bl2[0];
}

extern "C" void kernel_launch(void* const* d_in, const int* in_sizes, int n_in,
                              void* d_out, int out_size, void* d_ws, size_t ws_size,
                              hipStream_t stream) {
    const float* x   = (const float*)d_in[0];
    const float* W1  = (const float*)d_in[1];
    const float* b1  = (const float*)d_in[2];
    const float* W2  = (const float*)d_in[3];
    const float* b2  = (const float*)d_in[4];
    const float* Wl1 = (const float*)d_in[5];
    const float* bl1 = (const float*)d_in[6];
    const float* Wl2 = (const float*)d_in[7];
    const float* bl2 = (const float*)d_in[8];
    const int* ei    = (const int*)d_in[9];     // [2][NE]
    const int* batch = (const int*)d_in[10];
    float* out = (float*)d_out;

    const int* row = ei;
    const int* col = ei + NE;

    // workspace layout
    char* ws = (char*)d_ws;
    size_t off = 0;
    float* y       = (float*)(ws + off); off += (size_t)NN * HID * 4;   // 51.2 MB
    float* h       = (float*)(ws + off); off += (size_t)NN * HID * 4;   // 51.2 MB
    int*   degE    = (int*)  (ws + off); off += (size_t)NN * 4;
    float* dis     = (float*)(ws + off); off += (size_t)NN * 4;
    int*   startp  = (int*)  (ws + off); off += (size_t)(NN + 1) * 4;
    int*   partial = (int*)  (ws + off); off += 512 * 4;
    int*   csr     = (int*)  (ws + off); off += (size_t)NE * 4;         // 6.4 MB
    int*   gs      = (int*)  (ws + off); off += (size_t)(NG + 1) * 4;
    float* pooled  = (float*)(ws + off); off += (size_t)NG * HID * 4;   // 2 MB
    int*   bcur    = (int*)  (ws + off); off += (size_t)NBK * 4;
    int*   staging = (int*)h;   // aliases h: dead until layer-1 gather, CSR build done by then

    // ---- CSR build (bucketed two-pass counting sort) ----
    k_zero<<<(NBK + 255) / 256, 256, 0, stream>>>(bcur, NBK);
    k_bucket<<<NBB, 256, 0, stream>>>(row, col, bcur, staging);
    k_hist2<<<NBK, 256, 0, stream>>>(staging, bcur, degE, dis);
    k_scan1<<<NB, 256, 0, stream>>>(degE, startp, partial);
    k_scan2<<<1, 512, 0, stream>>>(partial);
    k_scan3<<<NB, 256, 0, stream>>>(startp, partial);
    k_fillb<<<NBK, 256, 0, stream>>>(staging, bcur, startp, csr);
    k_bounds<<<(NG + 256) / 256, 256, 0, stream>>>(batch, gs);

    // ---- layer 1 ----
    k_xw1<<<NN / 16, 256, 0, stream>>>(x, W1, dis, y);
    k_gather<<<NN / 4, 256, 0, stream>>>(y, startp, csr, dis, b1, h);

    // ---- layer 2 ----
    k_xw2<<<NN / 32, 256, 0, stream>>>(h, W2, dis, y);
    k_gather<<<NN / 4, 256, 0, stream>>>(y, startp, csr, dis, b2, h);

    // ---- pool + head ----
    k_pool<<<NG, 128, 0, stream>>>(h, gs, pooled);
    k_head<<<NG, 128, 0, stream>>>(pooled, Wl1, bl1, Wl2, bl2, out);
}

// Round 4
// 285.908 us; speedup vs baseline: 20.3699x; 1.4090x over previous
//
#include <hip/hip_runtime.h>

#define NN 100000      // nodes
#define NE 1600000     // edges (without self loops)
#define NF 11          // input features
#define HID 128
#define NG 4096        // graphs
#define NB 391         // scan blocks = ceil(NN/256)

#define BSH 7
#define BNODES 128     // nodes per bucket = 1<<BSH
#define NBK 782        // ceil(NN/BNODES)
#define CAP 3072       // staging capacity per bucket (avg 2046, +22 sigma)
#define EPB 8192       // edges per k_bucket block
#define NBB 196        // ceil(NE/EPB)

// ---- bf16 pack/unpack helpers (RNE, no-NaN data) ----
__device__ __forceinline__ unsigned short f2bf(float f) {
    unsigned u = __float_as_uint(f);
    return (unsigned short)((u + 0x7FFFu + ((u >> 16) & 1u)) >> 16);
}
__device__ __forceinline__ unsigned packbf(float a, float b) {
    return (unsigned)f2bf(a) | ((unsigned)f2bf(b) << 16);
}
__device__ __forceinline__ float bflo(unsigned v) { return __uint_as_float(v << 16); }
__device__ __forceinline__ float bfhi(unsigned v) { return __uint_as_float(v & 0xFFFF0000u); }

// ---- zero ints ----
__global__ void k_zero(int* __restrict__ p, int n) {
    int i = blockIdx.x * blockDim.x + threadIdx.x;
    if (i < n) p[i] = 0;
}

// ---- pass 1: bucket edges by col>>7 into staging (workgroup multisplit) ----
__global__ __launch_bounds__(256) void k_bucket(const int* __restrict__ row, const int* __restrict__ col,
                                                int* __restrict__ bcur, int* __restrict__ staging) {
    __shared__ int cnt[NBK];
    __shared__ int loc[NBK];
    const int tid = threadIdx.x;
    const int e0 = blockIdx.x * EPB;
    for (int i = tid; i < NBK; i += 256) { cnt[i] = 0; loc[i] = 0; }
    __syncthreads();
    int rb[32]; unsigned pay[32];
#pragma unroll
    for (int j = 0; j < 32; ++j) {
        int e = e0 + j * 256 + tid;
        int c = (e < NE) ? col[e] : -1;
        int r = (e < NE) ? row[e] : 0;
        rb[j] = (c >= 0) ? (c >> BSH) : -1;
        pay[j] = (unsigned)r | ((unsigned)(c & (BNODES - 1)) << 17);
        if (rb[j] >= 0) atomicAdd(&cnt[rb[j]], 1);
    }
    __syncthreads();
    for (int b = tid; b < NBK; b += 256) {
        int c = cnt[b];
        cnt[b] = (c > 0) ? atomicAdd(&bcur[b], c) : 0;
    }
    __syncthreads();
#pragma unroll
    for (int j = 0; j < 32; ++j) {
        if (rb[j] >= 0) {
            int p = cnt[rb[j]] + atomicAdd(&loc[rb[j]], 1);
            staging[rb[j] * CAP + p] = (int)pay[j];
        }
    }
}

// ---- pass 2a: per-bucket histogram -> degE, dis ----
__global__ __launch_bounds__(256) void k_hist2(const int* __restrict__ staging, const int* __restrict__ bcur,
                                               int* __restrict__ degE, float* __restrict__ dis) {
    __shared__ int cnt[BNODES];
    const int b = blockIdx.x, tid = threadIdx.x;
    if (tid < BNODES) cnt[tid] = 0;
    __syncthreads();
    const int sz = bcur[b];
    const int base = b * CAP;
    for (int i = tid; i < sz; i += 256)
        atomicAdd(&cnt[((unsigned)staging[base + i]) >> 17], 1);
    __syncthreads();
    int n = b * BNODES + tid;
    if (tid < BNODES && n < NN) {
        int d = cnt[tid];
        degE[n] = d;
        dis[n] = rsqrtf((float)(d + 1));
    }
}

// ---- 3-phase exclusive scan of degE -> startp ----
__global__ void k_scan1(const int* __restrict__ degE, int* __restrict__ startp, int* __restrict__ partial) {
    __shared__ int sh[256];
    int t = threadIdx.x, i = blockIdx.x * 256 + t;
    int v = (i < NN) ? degE[i] : 0;
    sh[t] = v; __syncthreads();
    for (int off = 1; off < 256; off <<= 1) {
        int u = (t >= off) ? sh[t - off] : 0; __syncthreads();
        sh[t] += u; __syncthreads();
    }
    if (i < NN) startp[i] = sh[t] - v;
    if (t == 255) partial[blockIdx.x] = sh[255];
}

__global__ void k_scan2(int* __restrict__ partial) {   // 1 block, 512 thr
    __shared__ int sh[512];
    int t = threadIdx.x;
    int v = (t < NB) ? partial[t] : 0;
    sh[t] = v; __syncthreads();
    for (int off = 1; off < 512; off <<= 1) {
        int u = (t >= off) ? sh[t - off] : 0; __syncthreads();
        sh[t] += u; __syncthreads();
    }
    if (t < NB) partial[t] = sh[t] - v;
}

__global__ void k_scan3(int* __restrict__ startp, const int* __restrict__ partial) {
    int i = blockIdx.x * 256 + threadIdx.x;
    if (i < NN) startp[i] += partial[blockIdx.x];
    if (i == 0) startp[NN] = NE;
}

// ---- pass 2b: per-bucket counting sort into final CSR ----
__global__ __launch_bounds__(256) void k_fillb(const int* __restrict__ staging, const int* __restrict__ bcur,
                                               const int* __restrict__ startp, int* __restrict__ csr) {
    __shared__ int cur[BNODES];
    const int b = blockIdx.x, tid = threadIdx.x;
    int n = b * BNODES + tid;
    if (tid < BNODES) cur[tid] = (n < NN) ? startp[n] : 0;
    __syncthreads();
    const int sz = bcur[b];
    const int base = b * CAP;
    for (int i = tid; i < sz; i += 256) {
        unsigned p = (unsigned)staging[base + i];
        int pos = atomicAdd(&cur[p >> 17], 1);
        csr[pos] = (int)(p & 0x1FFFF);
    }
}

// ---- y = bf16((x @ W1) * dis) ; 16 nodes per 256-thr block, 2 feats/thread ----
__global__ __launch_bounds__(256) void k_xw1(const float* __restrict__ x, const float* __restrict__ W1,
                                             const float* __restrict__ dis, unsigned* __restrict__ yb) {
    __shared__ float w1s[NF * HID];
    __shared__ float xs[16 * NF];
    const int tid = threadIdx.x;
    const int n0 = blockIdx.x * 16;
    for (int i = tid; i < NF * HID; i += 256) w1s[i] = W1[i];
    for (int i = tid; i < 16 * NF; i += 256) xs[i] = x[(size_t)n0 * NF + i];
    __syncthreads();
    const int f2 = tid & 63;     // feature pair
    const int sub = tid >> 6;    // 0..3
#pragma unroll
    for (int p = 0; p < 4; ++p) {
        int nl = p * 4 + sub;
        float s0 = 0.f, s1 = 0.f;
#pragma unroll
        for (int k = 0; k < NF; ++k) {
            float xv = xs[nl * NF + k];
            s0 = fmaf(xv, w1s[k * HID + f2 * 2], s0);
            s1 = fmaf(xv, w1s[k * HID + f2 * 2 + 1], s1);
        }
        int n = n0 + nl;
        float d = dis[n];
        yb[n * 64 + f2] = packbf(s0 * d, s1 * d);
    }
}

// ---- gather conv (bf16 in, bf16 out, f32 accumulate) ----
__global__ __launch_bounds__(256) void k_gather(const unsigned* __restrict__ yb,
                                                const int* __restrict__ startp,
                                                const int* __restrict__ csr_rows,
                                                const float* __restrict__ dis,
                                                const float* __restrict__ b,
                                                unsigned* __restrict__ hb) {
    const int node = blockIdx.x * 4 + (threadIdx.x >> 6);
    const int lane = threadIdx.x & 63;
    int s = startp[node], e = startp[node + 1];
    unsigned sv = yb[node * 64 + lane];           // self loop
    float ax = bflo(sv), ay = bfhi(sv);
    for (int i = s; i < e; i += 64) {
        int idx = (i + lane < e) ? csr_rows[i + lane] : 0;
        int m = min(64, e - i);
        int j = 0;
        for (; j + 7 < m; j += 8) {
            unsigned v[8];
#pragma unroll
            for (int u = 0; u < 8; ++u) {
                int r = __shfl(idx, j + u);
                v[u] = yb[r * 64 + lane];
            }
#pragma unroll
            for (int u = 0; u < 8; ++u) { ax += bflo(v[u]); ay += bfhi(v[u]); }
        }
        for (; j + 3 < m; j += 4) {
            unsigned v[4];
#pragma unroll
            for (int u = 0; u < 4; ++u) {
                int r = __shfl(idx, j + u);
                v[u] = yb[r * 64 + lane];
            }
#pragma unroll
            for (int u = 0; u < 4; ++u) { ax += bflo(v[u]); ay += bfhi(v[u]); }
        }
        for (; j < m; ++j) {
            int r = __shfl(idx, j);
            unsigned v = yb[r * 64 + lane];
            ax += bflo(v); ay += bfhi(v);
        }
    }
    float d = dis[node];
    float2 bb = ((const float2*)b)[lane];
    ax = fmaxf(fmaf(ax, d, bb.x), 0.f);
    ay = fmaxf(fmaf(ay, d, bb.y), 0.f);
    hb[node * 64 + lane] = packbf(ax, ay);
}

// ---- y2 = bf16((h @ W2) * dis) ; 32 nodes/block ----
__global__ __launch_bounds__(256) void k_xw2(const unsigned* __restrict__ hb, const float* __restrict__ W2,
                                             const float* __restrict__ dis, unsigned* __restrict__ yb) {
    __shared__ float w2s[HID * HID];   // 64 KB
    __shared__ float hs[32 * HID];     // 16 KB
    const int tid = threadIdx.x;
    const int n0 = blockIdx.x * 32;
    for (int i = tid; i < HID * HID; i += 256) w2s[i] = W2[i];
    for (int i = tid; i < 32 * 64; i += 256) {
        unsigned v = hb[(size_t)n0 * 64 + i];
        hs[i * 2] = bflo(v); hs[i * 2 + 1] = bfhi(v);
    }
    __syncthreads();
    const int f4 = tid & 31;
    const int g = tid >> 5;
    float4 acc[4];
#pragma unroll
    for (int j = 0; j < 4; ++j) acc[j] = make_float4(0.f, 0.f, 0.f, 0.f);
    const float4* w4 = (const float4*)w2s;
    const float4* h4 = (const float4*)hs;
    for (int k4 = 0; k4 < 32; ++k4) {
        float4 hv[4];
#pragma unroll
        for (int j = 0; j < 4; ++j) hv[j] = h4[(g * 4 + j) * 32 + k4];
#pragma unroll
        for (int kk = 0; kk < 4; ++kk) {
            float4 wv = w4[(k4 * 4 + kk) * 32 + f4];
#pragma unroll
            for (int j = 0; j < 4; ++j) {
                float hj = (&hv[j].x)[kk];
                acc[j].x = fmaf(hj, wv.x, acc[j].x);
                acc[j].y = fmaf(hj, wv.y, acc[j].y);
                acc[j].z = fmaf(hj, wv.z, acc[j].z);
                acc[j].w = fmaf(hj, wv.w, acc[j].w);
            }
        }
    }
#pragma unroll
    for (int j = 0; j < 4; ++j) {
        int n = n0 + g * 4 + j;
        float d = dis[n];
        uint2 o;
        o.x = packbf(acc[j].x * d, acc[j].y * d);
        o.y = packbf(acc[j].z * d, acc[j].w * d);
        ((uint2*)yb)[n * 32 + f4] = o;
    }
}

// ---- graph segment bounds on sorted batch ----
__global__ void k_bounds(const int* __restrict__ batch, int* __restrict__ gs) {
    int g = blockIdx.x * blockDim.x + threadIdx.x;
    if (g > NG) return;
    int lo = 0, hi = NN;
    while (lo < hi) {
        int mid = (lo + hi) >> 1;
        if (batch[mid] < g) lo = mid + 1; else hi = mid;
    }
    gs[g] = lo;
}

// ---- mean pool: block (64 thr) per graph, bf16 h in ----
__global__ __launch_bounds__(64) void k_pool(const unsigned* __restrict__ hb, const int* __restrict__ gs,
                                             float* __restrict__ pooled) {
    int g = blockIdx.x, f2 = threadIdx.x;
    int s = gs[g], e = gs[g + 1];
    float ax = 0.f, ay = 0.f;
    for (int n = s; n < e; ++n) {
        unsigned v = hb[(size_t)n * 64 + f2];
        ax += bflo(v); ay += bfhi(v);
    }
    float inv = 1.0f / (float)max(e - s, 1);
    pooled[(size_t)g * HID + f2 * 2] = ax * inv;
    pooled[(size_t)g * HID + f2 * 2 + 1] = ay * inv;
}

// ---- head: out = relu(pooled @ Wl1 + bl1) @ Wl2 + bl2 ----
__global__ __launch_bounds__(128) void k_head(const float* __restrict__ pooled,
                                              const float* __restrict__ Wl1, const float* __restrict__ bl1,
                                              const float* __restrict__ Wl2, const float* __restrict__ bl2,
                                              float* __restrict__ out) {
    __shared__ float p[HID];
    __shared__ float red[128];
    const int g = blockIdx.x, f = threadIdx.x;
    p[f] = pooled[(size_t)g * HID + f];
    __syncthreads();
    float s = bl1[f];
    for (int k = 0; k < HID; ++k) s = fmaf(p[k], Wl1[k * HID + f], s);
    s = fmaxf(s, 0.f);
    red[f] = s * Wl2[f];
    __syncthreads();
    for (int off = 64; off > 0; off >>= 1) {
        if (f < off) red[f] += red[f + off];
        __syncthreads();
    }
    if (f == 0) out[g] = red[0] + bl2[0];
}

extern "C" void kernel_launch(void* const* d_in, const int* in_sizes, int n_in,
                              void* d_out, int out_size, void* d_ws, size_t ws_size,
                              hipStream_t stream) {
    const float* x   = (const float*)d_in[0];
    const float* W1  = (const float*)d_in[1];
    const float* b1  = (const float*)d_in[2];
    const float* W2  = (const float*)d_in[3];
    const float* b2  = (const float*)d_in[4];
    const float* Wl1 = (const float*)d_in[5];
    const float* bl1 = (const float*)d_in[6];
    const float* Wl2 = (const float*)d_in[7];
    const float* bl2 = (const float*)d_in[8];
    const int* ei    = (const int*)d_in[9];     // [2][NE]
    const int* batch = (const int*)d_in[10];
    float* out = (float*)d_out;

    const int* row = ei;
    const int* col = ei + NE;

    // workspace layout
    char* ws = (char*)d_ws;
    size_t off = 0;
    unsigned* yb   = (unsigned*)(ws + off); off += (size_t)NN * 64 * 4;   // 25.6 MB (bf16 pairs)
    unsigned* hb   = (unsigned*)(ws + off); off += (size_t)NN * 64 * 4;   // 25.6 MB
    int*   degE    = (int*)  (ws + off); off += (size_t)NN * 4;
    float* dis     = (float*)(ws + off); off += (size_t)NN * 4;
    int*   startp  = (int*)  (ws + off); off += (size_t)(NN + 1) * 4;
    int*   partial = (int*)  (ws + off); off += 512 * 4;
    int*   csr     = (int*)  (ws + off); off += (size_t)NE * 4;           // 6.4 MB
    int*   gs      = (int*)  (ws + off); off += (size_t)(NG + 1) * 4;
    float* pooled  = (float*)(ws + off); off += (size_t)NG * HID * 4;     // 2 MB
    int*   bcur    = (int*)  (ws + off); off += (size_t)NBK * 4;
    int*   staging = (int*)hb;   // aliases hb: dead until layer-1 gather; 9.6 MB < 25.6 MB

    // ---- CSR build (bucketed two-pass counting sort) ----
    k_zero<<<(NBK + 255) / 256, 256, 0, stream>>>(bcur, NBK);
    k_bucket<<<NBB, 256, 0, stream>>>(row, col, bcur, staging);
    k_hist2<<<NBK, 256, 0, stream>>>(staging, bcur, degE, dis);
    k_scan1<<<NB, 256, 0, stream>>>(degE, startp, partial);
    k_scan2<<<1, 512, 0, stream>>>(partial);
    k_scan3<<<NB, 256, 0, stream>>>(startp, partial);
    k_fillb<<<NBK, 256, 0, stream>>>(staging, bcur, startp, csr);
    k_bounds<<<(NG + 256) / 256, 256, 0, stream>>>(batch, gs);

    // ---- layer 1 ----
    k_xw1<<<NN / 16, 256, 0, stream>>>(x, W1, dis, yb);
    k_gather<<<NN / 4, 256, 0, stream>>>(yb, startp, csr, dis, b1, hb);

    // ---- layer 2 ----
    k_xw2<<<NN / 32, 256, 0, stream>>>(hb, W2, dis, yb);
    k_gather<<<NN / 4, 256, 0, stream>>>(yb, startp, csr, dis, b2, hb);

    // ---- pool + head ----
    k_pool<<<NG, 64, 0, stream>>>(hb, gs, pooled);
    k_head<<<NG, 128, 0, stream>>>(pooled, Wl1, bl1, Wl2, bl2, out);
}

// Round 5
// 258.722 us; speedup vs baseline: 22.5103x; 1.1051x over previous
//
#include <hip/hip_runtime.h>

#define NN 100000      // nodes
#define NE 1600000     // edges (without self loops)
#define NF 11          // input features
#define HID 128
#define NG 4096        // graphs
#define NB 391         // scan blocks = ceil(NN/256)

#define BSH 7
#define BNODES 128     // nodes per bucket = 1<<BSH
#define NBK 782        // ceil(NN/BNODES)
#define CAP 3072       // staging capacity per bucket (avg 2046, +22 sigma)
#define EPB 8192       // edges per k_bucket block
#define NBB 196        // ceil(NE/EPB)

typedef short bf16x8 __attribute__((ext_vector_type(8)));
typedef float f32x4 __attribute__((ext_vector_type(4)));

// ---- bf16 pack/unpack helpers (RNE, no-NaN data) ----
__device__ __forceinline__ unsigned short f2bf(float f) {
    unsigned u = __float_as_uint(f);
    return (unsigned short)((u + 0x7FFFu + ((u >> 16) & 1u)) >> 16);
}
__device__ __forceinline__ unsigned packbf(float a, float b) {
    return (unsigned)f2bf(a) | ((unsigned)f2bf(b) << 16);
}
__device__ __forceinline__ float bflo(unsigned v) { return __uint_as_float(v << 16); }
__device__ __forceinline__ float bfhi(unsigned v) { return __uint_as_float(v & 0xFFFF0000u); }
__device__ __forceinline__ bf16x8 as_bf(uint4 u) { union { uint4 a; bf16x8 b; } v; v.a = u; return v.b; }

// ---- zero ints ----
__global__ void k_zero(int* __restrict__ p, int n) {
    int i = blockIdx.x * blockDim.x + threadIdx.x;
    if (i < n) p[i] = 0;
}

// ---- pass 1: bucket edges by col>>7 into staging (workgroup multisplit) ----
__global__ __launch_bounds__(256) void k_bucket(const int* __restrict__ row, const int* __restrict__ col,
                                                int* __restrict__ bcur, int* __restrict__ staging) {
    __shared__ int cnt[NBK];
    __shared__ int loc[NBK];
    const int tid = threadIdx.x;
    const int e0 = blockIdx.x * EPB;
    for (int i = tid; i < NBK; i += 256) { cnt[i] = 0; loc[i] = 0; }
    __syncthreads();
    int rb[32]; unsigned pay[32];
#pragma unroll
    for (int j = 0; j < 32; ++j) {
        int e = e0 + j * 256 + tid;
        int c = (e < NE) ? col[e] : -1;
        int r = (e < NE) ? row[e] : 0;
        rb[j] = (c >= 0) ? (c >> BSH) : -1;
        pay[j] = (unsigned)r | ((unsigned)(c & (BNODES - 1)) << 17);
        if (rb[j] >= 0) atomicAdd(&cnt[rb[j]], 1);
    }
    __syncthreads();
    for (int b = tid; b < NBK; b += 256) {
        int c = cnt[b];
        cnt[b] = (c > 0) ? atomicAdd(&bcur[b], c) : 0;
    }
    __syncthreads();
#pragma unroll
    for (int j = 0; j < 32; ++j) {
        if (rb[j] >= 0) {
            int p = cnt[rb[j]] + atomicAdd(&loc[rb[j]], 1);
            staging[rb[j] * CAP + p] = (int)pay[j];
        }
    }
}

// ---- pass 2a: per-bucket histogram -> degE, dis ----
__global__ __launch_bounds__(256) void k_hist2(const int* __restrict__ staging, const int* __restrict__ bcur,
                                               int* __restrict__ degE, float* __restrict__ dis) {
    __shared__ int cnt[BNODES];
    const int b = blockIdx.x, tid = threadIdx.x;
    if (tid < BNODES) cnt[tid] = 0;
    __syncthreads();
    const int sz = bcur[b];
    const int base = b * CAP;
    for (int i = tid; i < sz; i += 256)
        atomicAdd(&cnt[((unsigned)staging[base + i]) >> 17], 1);
    __syncthreads();
    int n = b * BNODES + tid;
    if (tid < BNODES && n < NN) {
        int d = cnt[tid];
        degE[n] = d;
        dis[n] = rsqrtf((float)(d + 1));
    }
}

// ---- 3-phase exclusive scan of degE -> startp ----
__global__ void k_scan1(const int* __restrict__ degE, int* __restrict__ startp, int* __restrict__ partial) {
    __shared__ int sh[256];
    int t = threadIdx.x, i = blockIdx.x * 256 + t;
    int v = (i < NN) ? degE[i] : 0;
    sh[t] = v; __syncthreads();
    for (int off = 1; off < 256; off <<= 1) {
        int u = (t >= off) ? sh[t - off] : 0; __syncthreads();
        sh[t] += u; __syncthreads();
    }
    if (i < NN) startp[i] = sh[t] - v;
    if (t == 255) partial[blockIdx.x] = sh[255];
}

__global__ void k_scan2(int* __restrict__ partial) {   // 1 block, 512 thr
    __shared__ int sh[512];
    int t = threadIdx.x;
    int v = (t < NB) ? partial[t] : 0;
    sh[t] = v; __syncthreads();
    for (int off = 1; off < 512; off <<= 1) {
        int u = (t >= off) ? sh[t - off] : 0; __syncthreads();
        sh[t] += u; __syncthreads();
    }
    if (t < NB) partial[t] = sh[t] - v;
}

__global__ void k_scan3(int* __restrict__ startp, const int* __restrict__ partial) {
    int i = blockIdx.x * 256 + threadIdx.x;
    if (i < NN) startp[i] += partial[blockIdx.x];
    if (i == 0) startp[NN] = NE;
}

// ---- pass 2b: per-bucket counting sort into final CSR ----
__global__ __launch_bounds__(256) void k_fillb(const int* __restrict__ staging, const int* __restrict__ bcur,
                                               const int* __restrict__ startp, int* __restrict__ csr) {
    __shared__ int cur[BNODES];
    const int b = blockIdx.x, tid = threadIdx.x;
    int n = b * BNODES + tid;
    if (tid < BNODES) cur[tid] = (n < NN) ? startp[n] : 0;
    __syncthreads();
    const int sz = bcur[b];
    const int base = b * CAP;
    for (int i = tid; i < sz; i += 256) {
        unsigned p = (unsigned)staging[base + i];
        int pos = atomicAdd(&cur[p >> 17], 1);
        csr[pos] = (int)(p & 0x1FFFF);
    }
}

// ---- pack W2 (f32 [128][128], k-major) -> bf16 k-pairs per col: w2t[col*64 + k/2] ----
__global__ void k_w2t(const float* __restrict__ W2, unsigned* __restrict__ w2t) {
    int i = blockIdx.x * 256 + threadIdx.x;
    if (i >= HID * 64) return;
    int col = i >> 6, kw = i & 63;
    w2t[col * 64 + kw] = packbf(W2[(2 * kw) * HID + col], W2[(2 * kw + 1) * HID + col]);
}

// ---- y = bf16((x @ W1) * dis) ; 16 nodes per 256-thr block, 2 feats/thread ----
__global__ __launch_bounds__(256) void k_xw1(const float* __restrict__ x, const float* __restrict__ W1,
                                             const float* __restrict__ dis, unsigned* __restrict__ yb) {
    __shared__ float w1s[NF * HID];
    __shared__ float xs[16 * NF];
    const int tid = threadIdx.x;
    const int n0 = blockIdx.x * 16;
    for (int i = tid; i < NF * HID; i += 256) w1s[i] = W1[i];
    for (int i = tid; i < 16 * NF; i += 256) xs[i] = x[(size_t)n0 * NF + i];
    __syncthreads();
    const int f2 = tid & 63;     // feature pair
    const int sub = tid >> 6;    // 0..3
#pragma unroll
    for (int p = 0; p < 4; ++p) {
        int nl = p * 4 + sub;
        float s0 = 0.f, s1 = 0.f;
#pragma unroll
        for (int k = 0; k < NF; ++k) {
            float xv = xs[nl * NF + k];
            s0 = fmaf(xv, w1s[k * HID + f2 * 2], s0);
            s1 = fmaf(xv, w1s[k * HID + f2 * 2 + 1], s1);
        }
        int n = n0 + nl;
        float d = dis[n];
        yb[n * 64 + f2] = packbf(s0 * d, s1 * d);
    }
}

// ---- gather conv (bf16 in, bf16 out, f32 accumulate) ----
__global__ __launch_bounds__(256) void k_gather(const unsigned* __restrict__ yb,
                                                const int* __restrict__ startp,
                                                const int* __restrict__ csr_rows,
                                                const float* __restrict__ dis,
                                                const float* __restrict__ b,
                                                unsigned* __restrict__ hb) {
    const int node = blockIdx.x * 4 + (threadIdx.x >> 6);
    const int lane = threadIdx.x & 63;
    int s = startp[node], e = startp[node + 1];
    unsigned sv = yb[node * 64 + lane];           // self loop
    float ax = bflo(sv), ay = bfhi(sv);
    for (int i = s; i < e; i += 64) {
        int idx = (i + lane < e) ? csr_rows[i + lane] : 0;
        int m = min(64, e - i);
        int j = 0;
        for (; j + 7 < m; j += 8) {
            unsigned v[8];
#pragma unroll
            for (int u = 0; u < 8; ++u) {
                int r = __shfl(idx, j + u);
                v[u] = yb[r * 64 + lane];
            }
#pragma unroll
            for (int u = 0; u < 8; ++u) { ax += bflo(v[u]); ay += bfhi(v[u]); }
        }
        for (; j + 3 < m; j += 4) {
            unsigned v[4];
#pragma unroll
            for (int u = 0; u < 4; ++u) {
                int r = __shfl(idx, j + u);
                v[u] = yb[r * 64 + lane];
            }
#pragma unroll
            for (int u = 0; u < 4; ++u) { ax += bflo(v[u]); ay += bfhi(v[u]); }
        }
        for (; j < m; ++j) {
            int r = __shfl(idx, j);
            unsigned v = yb[r * 64 + lane];
            ax += bflo(v); ay += bfhi(v);
        }
    }
    float d = dis[node];
    float2 bb = ((const float2*)b)[lane];
    ax = fmaxf(fmaf(ax, d, bb.x), 0.f);
    ay = fmaxf(fmaf(ay, d, bb.y), 0.f);
    hb[node * 64 + lane] = packbf(ax, ay);
}

// ---- y2 = bf16((h @ W2) * dis) via MFMA ; 64 nodes x 128 cols per 256-thr block ----
__global__ __launch_bounds__(256) void k_xw2m(const unsigned* __restrict__ hb,
                                              const unsigned* __restrict__ w2t,
                                              const float* __restrict__ dis,
                                              unsigned* __restrict__ yb) {
    const int tid = threadIdx.x;
    const int wid = tid >> 6, lane = tid & 63;
    const int lr = lane & 15, lk = lane >> 4;
    const int n0 = blockIdx.x * 64;
    const int colb = wid * 32;
    const uint4* h4 = (const uint4*)hb;
    const uint4* w4 = (const uint4*)w2t;

    // B fragments: lane holds B[k0..k0+7][col], col = colb + c*16 + lr, k0 = lk*8 + ks*32
    bf16x8 Bf[2][4];
#pragma unroll
    for (int c = 0; c < 2; ++c)
#pragma unroll
        for (int ks = 0; ks < 4; ++ks)
            Bf[c][ks] = as_bf(w4[(colb + c * 16 + lr) * 16 + ks * 4 + lk]);

    f32x4 acc[4][2];
#pragma unroll
    for (int r = 0; r < 4; ++r)
#pragma unroll
        for (int c = 0; c < 2; ++c) {
            f32x4 z = {0.f, 0.f, 0.f, 0.f};
            acc[r][c] = z;
        }

#pragma unroll
    for (int ks = 0; ks < 4; ++ks) {
        bf16x8 Af[4];
#pragma unroll
        for (int r = 0; r < 4; ++r)
            Af[r] = as_bf(h4[(size_t)(n0 + r * 16 + lr) * 16 + ks * 4 + lk]);
#pragma unroll
        for (int r = 0; r < 4; ++r)
#pragma unroll
            for (int c = 0; c < 2; ++c)
                acc[r][c] = __builtin_amdgcn_mfma_f32_16x16x32_bf16(Af[r], Bf[c][ks], acc[r][c], 0, 0, 0);
    }

    // C/D layout: col = lane&15, row = lk*4 + i
#pragma unroll
    for (int r = 0; r < 4; ++r) {
#pragma unroll
        for (int i = 0; i < 4; ++i) {
            int nd = n0 + r * 16 + lk * 4 + i;
            float d = (nd < NN) ? dis[nd] : 0.f;
#pragma unroll
            for (int c = 0; c < 2; ++c) {
                float v = acc[r][c][i] * d;
                float o = __shfl_xor(v, 1);
                if (!(lane & 1) && nd < NN) {
                    int col = colb + c * 16 + lr;
                    yb[nd * 64 + (col >> 1)] = packbf(v, o);
                }
            }
        }
    }
}

// ---- graph segment bounds on sorted batch ----
__global__ void k_bounds(const int* __restrict__ batch, int* __restrict__ gs) {
    int g = blockIdx.x * blockDim.x + threadIdx.x;
    if (g > NG) return;
    int lo = 0, hi = NN;
    while (lo < hi) {
        int mid = (lo + hi) >> 1;
        if (batch[mid] < g) lo = mid + 1; else hi = mid;
    }
    gs[g] = lo;
}

// ---- mean pool: block (64 thr) per graph, bf16 h in ----
__global__ __launch_bounds__(64) void k_pool(const unsigned* __restrict__ hb, const int* __restrict__ gs,
                                             float* __restrict__ pooled) {
    int g = blockIdx.x, f2 = threadIdx.x;
    int s = gs[g], e = gs[g + 1];
    float ax = 0.f, ay = 0.f;
    for (int n = s; n < e; ++n) {
        unsigned v = hb[(size_t)n * 64 + f2];
        ax += bflo(v); ay += bfhi(v);
    }
    float inv = 1.0f / (float)max(e - s, 1);
    pooled[(size_t)g * HID + f2 * 2] = ax * inv;
    pooled[(size_t)g * HID + f2 * 2 + 1] = ay * inv;
}

// ---- head: out = relu(pooled @ Wl1 + bl1) @ Wl2 + bl2 ----
__global__ __launch_bounds__(128) void k_head(const float* __restrict__ pooled,
                                              const float* __restrict__ Wl1, const float* __restrict__ bl1,
                                              const float* __restrict__ Wl2, const float* __restrict__ bl2,
                                              float* __restrict__ out) {
    __shared__ float p[HID];
    __shared__ float red[128];
    const int g = blockIdx.x, f = threadIdx.x;
    p[f] = pooled[(size_t)g * HID + f];
    __syncthreads();
    float s = bl1[f];
    for (int k = 0; k < HID; ++k) s = fmaf(p[k], Wl1[k * HID + f], s);
    s = fmaxf(s, 0.f);
    red[f] = s * Wl2[f];
    __syncthreads();
    for (int off = 64; off > 0; off >>= 1) {
        if (f < off) red[f] += red[f + off];
        __syncthreads();
    }
    if (f == 0) out[g] = red[0] + bl2[0];
}

extern "C" void kernel_launch(void* const* d_in, const int* in_sizes, int n_in,
                              void* d_out, int out_size, void* d_ws, size_t ws_size,
                              hipStream_t stream) {
    const float* x   = (const float*)d_in[0];
    const float* W1  = (const float*)d_in[1];
    const float* b1  = (const float*)d_in[2];
    const float* W2  = (const float*)d_in[3];
    const float* b2  = (const float*)d_in[4];
    const float* Wl1 = (const float*)d_in[5];
    const float* bl1 = (const float*)d_in[6];
    const float* Wl2 = (const float*)d_in[7];
    const float* bl2 = (const float*)d_in[8];
    const int* ei    = (const int*)d_in[9];     // [2][NE]
    const int* batch = (const int*)d_in[10];
    float* out = (float*)d_out;

    const int* row = ei;
    const int* col = ei + NE;

    // workspace layout
    char* ws = (char*)d_ws;
    size_t off = 0;
    unsigned* yb   = (unsigned*)(ws + off); off += (size_t)NN * 64 * 4;   // 25.6 MB (bf16 pairs)
    unsigned* hb   = (unsigned*)(ws + off); off += (size_t)NN * 64 * 4;   // 25.6 MB
    int*   degE    = (int*)  (ws + off); off += (size_t)NN * 4;
    float* dis     = (float*)(ws + off); off += (size_t)NN * 4;
    int*   startp  = (int*)  (ws + off); off += (size_t)(NN + 1) * 4;
    int*   partial = (int*)  (ws + off); off += 512 * 4;
    int*   csr     = (int*)  (ws + off); off += (size_t)NE * 4;           // 6.4 MB
    int*   gs      = (int*)  (ws + off); off += (size_t)(NG + 1) * 4;
    float* pooled  = (float*)(ws + off); off += (size_t)NG * HID * 4;     // 2 MB
    int*   bcur    = (int*)  (ws + off); off += (size_t)NBK * 4;
    unsigned* w2t  = (unsigned*)(ws + off); off += (size_t)HID * 64 * 4;  // 32 KB
    int*   staging = (int*)hb;   // aliases hb: dead until layer-1 gather; 9.6 MB < 25.6 MB

    // ---- CSR build (bucketed two-pass counting sort) ----
    k_zero<<<(NBK + 255) / 256, 256, 0, stream>>>(bcur, NBK);
    k_bucket<<<NBB, 256, 0, stream>>>(row, col, bcur, staging);
    k_hist2<<<NBK, 256, 0, stream>>>(staging, bcur, degE, dis);
    k_scan1<<<NB, 256, 0, stream>>>(degE, startp, partial);
    k_scan2<<<1, 512, 0, stream>>>(partial);
    k_scan3<<<NB, 256, 0, stream>>>(startp, partial);
    k_fillb<<<NBK, 256, 0, stream>>>(staging, bcur, startp, csr);
    k_bounds<<<(NG + 256) / 256, 256, 0, stream>>>(batch, gs);
    k_w2t<<<(HID * 64 + 255) / 256, 256, 0, stream>>>(W2, w2t);

    // ---- layer 1 ----
    k_xw1<<<NN / 16, 256, 0, stream>>>(x, W1, dis, yb);
    k_gather<<<NN / 4, 256, 0, stream>>>(yb, startp, csr, dis, b1, hb);

    // ---- layer 2 (MFMA) ----
    k_xw2m<<<(NN + 63) / 64, 256, 0, stream>>>(hb, w2t, dis, yb);
    k_gather<<<NN / 4, 256, 0, stream>>>(yb, startp, csr, dis, b2, hb);

    // ---- pool + head ----
    k_pool<<<NG, 64, 0, stream>>>(hb, gs, pooled);
    k_head<<<NG, 128, 0, stream>>>(pooled, Wl1, bl1, Wl2, bl2, out);
}